// Round 5
// baseline (1007.934 us; speedup 1.0000x reference)
//
#include <hip/hip_runtime.h>

typedef unsigned short u16;
typedef unsigned int u32;
typedef __attribute__((ext_vector_type(8))) short short8;
typedef __attribute__((ext_vector_type(4))) float f32x4;

// Problem constants: B=16, N=256, T=4096, D=1024, H=8, DH=128
#define SCALE 0.08838834764831845f
#define OUT_ELEMS 33554432ull  // 16*256*8*1024

__device__ __forceinline__ u16 f2b(float f) {  // f32 -> bf16 RNE
  u32 u = __float_as_uint(f);
  u32 r = u + 0x7fffu + ((u >> 16) & 1u);
  return (u16)(r >> 16);
}

__device__ __forceinline__ u32 cvtpk(float lo, float hi) {  // 2 f32 -> packed bf16x2 (RNE)
  u32 r;
  asm("v_cvt_pk_bf16_f32 %0, %1, %2" : "=v"(r) : "v"(lo), "v"(hi));
  return r;
}

__device__ __forceinline__ void gload16(const void* g, void* l) {
  // async global->LDS, 16B per lane; LDS dest = wave-uniform base (+ lane*16 by HW)
  __builtin_amdgcn_global_load_lds((const __attribute__((address_space(1))) void*)g,
                                   (__attribute__((address_space(3))) void*)l, 16, 0, 0);
}

// ---------------- LayerNorm rows of length 1024 -> bf16 (scale folded) -------
__global__ __launch_bounds__(256) void ln_rows(const float* __restrict__ in,
                                               const float* __restrict__ gamma,
                                               u16* __restrict__ out, float scale) {
  const int row = blockIdx.x;
  const int t = threadIdx.x;
  const float4 v = *(const float4*)(in + (size_t)row * 1024 + t * 4);
  float s = v.x + v.y + v.z + v.w;
  float q = v.x * v.x + v.y * v.y + v.z * v.z + v.w * v.w;
#pragma unroll
  for (int m = 32; m; m >>= 1) {
    s += __shfl_down(s, m);
    q += __shfl_down(q, m);
  }
  __shared__ float red[8];
  const int w = t >> 6;
  if ((t & 63) == 0) { red[w] = s; red[4 + w] = q; }
  __syncthreads();
  s = red[0] + red[1] + red[2] + red[3];
  q = red[4] + red[5] + red[6] + red[7];
  const float mu = s * (1.0f / 1024.0f);
  const float var = q * (1.0f / 1024.0f) - mu * mu;
  const float rs = rsqrtf(var + 1e-5f) * scale;
  const float4 g = *(const float4*)(gamma + t * 4);
  ushort4 o;
  o.x = f2b((v.x - mu) * rs * g.x);
  o.y = f2b((v.y - mu) * rs * g.y);
  o.z = f2b((v.z - mu) * rs * g.z);
  o.w = f2b((v.w - mu) * rs * g.w);
  *(ushort4*)(out + (size_t)row * 1024 + t * 4) = o;
}

// ---------------- W_kv[:, :128] -> Wt bf16 [128][1024] -----------------------
__global__ __launch_bounds__(256) void cvt_w(const float* __restrict__ w, u16* __restrict__ wt) {
  const int n = blockIdx.x;  // 0..127
  const int t = threadIdx.x;
  const int d = t * 4;
  ushort4 o;
  o.x = f2b(w[(size_t)(d + 0) * 256 + n]);
  o.y = f2b(w[(size_t)(d + 1) * 256 + n]);
  o.z = f2b(w[(size_t)(d + 2) * 256 + n]);
  o.w = f2b(w[(size_t)(d + 3) * 256 + n]);
  *(ushort4*)(wt + (size_t)n * 1024 + d) = o;
}

// ---------------- x_n [b][4096][1024] -> x_nT [b][1024][4096] (bf16) ---------
__global__ __launch_bounds__(256) void transpose_xn(const u16* __restrict__ xn,
                                                    u16* __restrict__ xnt) {
  const int jt = blockIdx.x, dt = blockIdx.y, b = blockIdx.z;
  __shared__ u16 tile[64][72];  // pad 8 keeps 16B alignment per row
  const int t = threadIdx.x;
  const size_t src = ((size_t)b * 4096 + jt * 64) * 1024 + dt * 64;
#pragma unroll
  for (int p = 0; p < 2; ++p) {
    const int idx = t + 256 * p;
    const int j = idx >> 3, c = idx & 7;
    *(short8*)(&tile[j][c * 8]) = *(const short8*)(xn + src + (size_t)j * 1024 + c * 8);
  }
  __syncthreads();
  const size_t dst = ((size_t)b * 1024 + dt * 64) * 4096 + jt * 64;
#pragma unroll
  for (int p = 0; p < 2; ++p) {
    const int idx = t + 256 * p;
    const int d = idx >> 3, jj = idx & 7;
    short8 o;
#pragma unroll
    for (int e = 0; e < 8; ++e) o[e] = (short)tile[jj * 8 + e][d];
    *(short8*)(xnt + dst + (size_t)d * 4096 + jj * 8) = o;
  }
}

// ---------------- k = x_n @ W[:, :128]  (M=65536, N=128, K=1024) -------------
__global__ __launch_bounds__(256) void kgemm(const u16* __restrict__ xn,
                                             const u16* __restrict__ wt,
                                             u16* __restrict__ ks) {
  __shared__ u16 As[128 * 32];
  __shared__ u16 Bs[128 * 32];
  const int t = threadIdx.x;
  const int lane = t & 63, w = t >> 6;
  const int wm = w >> 1, wn = w & 1;
  const int j0 = blockIdx.x * 128;
  const int g = lane >> 4, r16 = lane & 15;
  f32x4 acc[4][4] = {};
  for (int k0 = 0; k0 < 1024; k0 += 32) {
    __syncthreads();
#pragma unroll
    for (int i = 0; i < 2; ++i) {
      const int seg = i * 4 + w;
      const int off = seg * 1024 + lane * 16;  // linear LDS byte offset
      const int row = off >> 6;                // 64B per row (32 bf16)
      const int c = (off >> 4) & 3;            // 16B chunk in row
      const int sw = c ^ ((row >> 1) & 3);     // inverse-swizzled global source
      gload16(xn + ((size_t)(j0 + row)) * 1024 + k0 + sw * 8, (char*)As + seg * 1024);
      gload16(wt + ((size_t)row) * 1024 + k0 + sw * 8, (char*)Bs + seg * 1024);
    }
    __syncthreads();
    short8 a[4], bq[4];
#pragma unroll
    for (int mt = 0; mt < 4; ++mt) {
      const int row = wm * 64 + mt * 16 + r16;
      const int sw = g ^ ((row >> 1) & 3);
      a[mt] = *(const short8*)(As + row * 32 + sw * 8);
    }
#pragma unroll
    for (int nt = 0; nt < 4; ++nt) {
      const int row = wn * 64 + nt * 16 + r16;
      const int sw = g ^ ((row >> 1) & 3);
      bq[nt] = *(const short8*)(Bs + row * 32 + sw * 8);
    }
#pragma unroll
    for (int mt = 0; mt < 4; ++mt)
#pragma unroll
      for (int nt = 0; nt < 4; ++nt)
        acc[mt][nt] = __builtin_amdgcn_mfma_f32_16x16x32_bf16(a[mt], bq[nt], acc[mt][nt], 0, 0, 0);
  }
#pragma unroll
  for (int mt = 0; mt < 4; ++mt)
#pragma unroll
    for (int nt = 0; nt < 4; ++nt)
#pragma unroll
      for (int r = 0; r < 4; ++r) {
        const int j = j0 + wm * 64 + mt * 16 + g * 4 + r;
        const int n = wn * 64 + nt * 16 + r16;
        ks[(size_t)j * 128 + n] = f2b(acc[mt][nt][r]);
      }
}

// ---------------- sim + softmax -> attn (f32 only) ---------------------------
// block = (b, h, 16 q-rows); 16 waves, wave w covers j in [w*256, w*256+256).
// SWAPPED QK^T: acc = mfma(K_frag, Q_frag) -> lane holds col i = r16 (q-row),
// rows j = g*4 + r (consecutive). Full-line dwordx4 stores, shfl-only reduce.
__global__ __launch_bounds__(1024) void attn_kernel(const u16* __restrict__ qs,
                                                    const u16* __restrict__ ks,
                                                    float* __restrict__ attn) {
  const int blk = blockIdx.x;
  const int it = blk & 15, h = (blk >> 4) & 7, b = blk >> 7;
  const int i0 = it * 16;
  const int t = threadIdx.x;
  const int lane = t & 63, w = t >> 6;
  const int g = lane >> 4, r16 = lane & 15;
  __shared__ u16 Q[16 * 128];
  __shared__ float redm[256];
  __shared__ float reds[256];
  if (t < 256) {
    const int row = t >> 4, c = t & 15;
    const int sw = c ^ (row & 7);
    *(short8*)(Q + row * 128 + sw * 8) =
        *(const short8*)(qs + ((size_t)(b * 256 + i0 + row)) * 1024 + h * 128 + c * 8);
  }
  __syncthreads();
  short8 a[4];
#pragma unroll
  for (int kp = 0; kp < 4; ++kp) {
    const int c = kp * 4 + g;
    const int sw = c ^ (r16 & 7);
    a[kp] = *(const short8*)(Q + r16 * 128 + sw * 8);
  }
  const u16* kb = ks + (size_t)b * 4096 * 128;
  const int j0 = w * 256;
  f32x4 acc[16] = {};
#pragma unroll
  for (int kp = 0; kp < 4; ++kp) {
#pragma unroll
    for (int nt = 0; nt < 16; ++nt) {
      const short8 bv = *(const short8*)(kb + (size_t)(j0 + nt * 16 + r16) * 128 + kp * 32 + g * 8);
      // swapped: K rows are the M dim (j), Q rows are the N dim (i)
      acc[nt] = __builtin_amdgcn_mfma_f32_16x16x32_bf16(bv, a[kp], acc[nt], 0, 0, 0);
    }
  }
  // lane holds 64 values: j = j0 + nt*16 + g*4 + r, all for q-row i = r16
  float mx = acc[0][0];
#pragma unroll
  for (int nt = 0; nt < 16; ++nt)
#pragma unroll
    for (int r = 0; r < 4; ++r) mx = fmaxf(mx, acc[nt][r]);
  mx = fmaxf(mx, __shfl_xor(mx, 16));
  mx = fmaxf(mx, __shfl_xor(mx, 32));  // max over this wave's 256 j, per row r16
  if (lane < 16) redm[w * 16 + lane] = mx;
  __syncthreads();
  float m = redm[r16];
#pragma unroll
  for (int w2 = 1; w2 < 16; ++w2) m = fmaxf(m, redm[w2 * 16 + r16]);
  float sm = 0.f;
#pragma unroll
  for (int nt = 0; nt < 16; ++nt)
#pragma unroll
    for (int r = 0; r < 4; ++r) {
      const float p = __expf(acc[nt][r] - m);
      acc[nt][r] = p;
      sm += p;
    }
  sm += __shfl_xor(sm, 16);
  sm += __shfl_xor(sm, 32);
  if (lane < 16) reds[w * 16 + lane] = sm;
  __syncthreads();
  float s = reds[r16];
#pragma unroll
  for (int w2 = 1; w2 < 16; ++w2) s += reds[w2 * 16 + r16];
  const float inv = 1.0f / s;
#pragma unroll
  for (int nt = 0; nt < 16; ++nt) acc[nt] *= inv;

  // f32 attn: 16 dwordx4 stores, each instr = 16 rows x 64B full aligned lines
  float* arow = attn + ((size_t)((b * 8 + h) * 256 + i0 + r16)) * 4096 + j0;
#pragma unroll
  for (int nt = 0; nt < 16; ++nt)
    *(f32x4*)(arow + nt * 16 + g * 4) = acc[nt];
}

// ---------------- out = attn(f32) @ x_nT  256x256, counted-vmcnt + A-cvt -----
// Per (b,h): C[256 x 1024] = attn[256 x 4096] @ xnt panel. Grid 512 = 16b*8h*4ft.
// 8 waves (2M x 4N), wave tile 128x64, acc[8][4]. BK=32, dbuf 64KB LDS.
// A path: f32 reg-stage (4 dwordx4) -> cvt_pk bf16 -> ds_write (T14, hidden
// under MFMA). B path: global_load_lds. vmcnt: mid-iter (2) = A regs ready,
// B flying; end-iter (6) = B(t+1) drained, G(t+2) in flight. Never 0 mid-loop.
__global__ __launch_bounds__(512, 2) void ogemm256(const float* __restrict__ attn,
                                                   const u16* __restrict__ xnt,
                                                   float* __restrict__ out) {
  __shared__ char S[65536];  // A dbuf [0,32K), B dbuf [32K,64K); 16KB per buf
  const int orig = blockIdx.x;
  const int wid = (orig & 7) * 64 + (orig >> 3);  // XCD-chunked, bijective (512%8==0)
  const int b = wid >> 5, ft = (wid >> 3) & 3, h = wid & 7;  // 8 h share B panel
  const int t = threadIdx.x;
  const int lane = t & 63, w = t >> 6;
  const int wm = w >> 2, wn = w & 3;  // 2 x 4 waves
  const int g = lane >> 4, r16 = lane & 15;
  const float* Ab = attn + ((size_t)(b * 8 + h) * 256) * 4096;
  const u16* Bb = xnt + ((size_t)b * 1024 + ft * 256) * 4096;

  // A staging coords: thread -> (row=t>>1, half=t&1), 16 f32 = 4 float4/tile
  const int arow = t >> 1, ahalf = t & 1;
  const float* ap = Ab + (size_t)arow * 4096 + ahalf * 16;
  const int asw = (arow & 3) ^ ((arow >> 2) & 3);
  const int apos0 = arow * 64 + (((ahalf * 2 + 0) ^ asw) * 16);
  const int apos1 = arow * 64 + (((ahalf * 2 + 1) ^ asw) * 16);
  // B staging: 2 gload16/thread, rows t>>2 and 128+(t>>2); inverse swizzle src
  const int lin0 = t * 16;
  const int row0 = lin0 >> 6;
  const int sc0 = ((lin0 >> 4) & 3) ^ (row0 & 3) ^ ((row0 >> 2) & 3);
  const int lin1 = 8192 + t * 16;
  const int row1 = lin1 >> 6;
  const int sc1 = ((lin1 >> 4) & 3) ^ (row1 & 3) ^ ((row1 >> 2) & 3);
  const int wuni = w * 1024;  // wave-uniform LDS offset within a seg

  f32x4 acc[8][4] = {};
  float4 v0, v1, v2, v3;

  // ---- prologue: A0 regs + B0 ; cvt A0 -> bufA0 ; A1 regs + B1 ----
  v0 = *(const float4*)(ap + 0);
  v1 = *(const float4*)(ap + 4);
  v2 = *(const float4*)(ap + 8);
  v3 = *(const float4*)(ap + 12);
  gload16(Bb + (size_t)row0 * 4096 + sc0 * 8, S + 32768 + wuni);
  gload16(Bb + (size_t)row1 * 4096 + sc1 * 8, S + 32768 + 8192 + wuni);
  asm volatile("s_waitcnt vmcnt(2)" ::: "memory");  // A0 regs ready, B0 flying
  {
    uint4 q0 = {cvtpk(v0.x, v0.y), cvtpk(v0.z, v0.w), cvtpk(v1.x, v1.y), cvtpk(v1.z, v1.w)};
    uint4 q1 = {cvtpk(v2.x, v2.y), cvtpk(v2.z, v2.w), cvtpk(v3.x, v3.y), cvtpk(v3.z, v3.w)};
    *(uint4*)(S + apos0) = q0;
    *(uint4*)(S + apos1) = q1;
  }
  v0 = *(const float4*)(ap + 32 + 0);
  v1 = *(const float4*)(ap + 32 + 4);
  v2 = *(const float4*)(ap + 32 + 8);
  v3 = *(const float4*)(ap + 32 + 12);
  gload16(Bb + (size_t)row0 * 4096 + 32 + sc0 * 8, S + 32768 + 16384 + wuni);
  gload16(Bb + (size_t)row1 * 4096 + 32 + sc1 * 8, S + 32768 + 16384 + 8192 + wuni);
  asm volatile("s_waitcnt vmcnt(6)" ::: "memory");  // B0 done; A1+B1 in flight
  asm volatile("s_waitcnt lgkmcnt(0)" ::: "memory");
  __builtin_amdgcn_sched_barrier(0);
  __builtin_amdgcn_s_barrier();

  const int ch = (g ^ (r16 & 3) ^ ((r16 >> 2) & 3)) * 16;
  for (int t64 = 0; t64 < 128; ++t64) {
    const int buf = t64 & 1;
    const char* A0 = S + buf * 16384;
    const char* B0 = S + 32768 + buf * 16384;
    short8 af[8], bf[4];
#pragma unroll
    for (int mt = 0; mt < 8; ++mt)
      af[mt] = *(const short8*)(A0 + (wm * 128 + mt * 16 + r16) * 64 + ch);
#pragma unroll
    for (int nt = 0; nt < 4; ++nt)
      bf[nt] = *(const short8*)(B0 + (wn * 64 + nt * 16 + r16) * 64 + ch);
    asm volatile("s_waitcnt vmcnt(2)" ::: "memory");  // A(t+1) regs ready
    if (t64 + 1 < 128) {  // cvt A(t+1) -> bufA^1 (readers finished last iter)
      uint4 q0 = {cvtpk(v0.x, v0.y), cvtpk(v0.z, v0.w), cvtpk(v1.x, v1.y), cvtpk(v1.z, v1.w)};
      uint4 q1 = {cvtpk(v2.x, v2.y), cvtpk(v2.z, v2.w), cvtpk(v3.x, v3.y), cvtpk(v3.z, v3.w)};
      *(uint4*)(S + (buf ^ 1) * 16384 + apos0) = q0;
      *(uint4*)(S + (buf ^ 1) * 16384 + apos1) = q1;
    }
    asm volatile("s_waitcnt lgkmcnt(0)" ::: "memory");
    __builtin_amdgcn_sched_barrier(0);
    __builtin_amdgcn_s_barrier();  // all waves done reading buf; bufA^1 filled
    if (t64 + 2 < 128) {  // issue G(t+2): A regs + B -> bufB (current, now free)
      const int k0 = (t64 + 2) * 32;
      v0 = *(const float4*)(ap + k0 + 0);
      v1 = *(const float4*)(ap + k0 + 4);
      v2 = *(const float4*)(ap + k0 + 8);
      v3 = *(const float4*)(ap + k0 + 12);
      gload16(Bb + (size_t)row0 * 4096 + k0 + sc0 * 8, S + 32768 + buf * 16384 + wuni);
      gload16(Bb + (size_t)row1 * 4096 + k0 + sc1 * 8, S + 32768 + buf * 16384 + 8192 + wuni);
    }
    __builtin_amdgcn_s_setprio(1);
#pragma unroll
    for (int mt = 0; mt < 8; ++mt)
#pragma unroll
      for (int nt = 0; nt < 4; ++nt)
        acc[mt][nt] = __builtin_amdgcn_mfma_f32_16x16x32_bf16(af[mt], bf[nt], acc[mt][nt], 0, 0, 0);
    __builtin_amdgcn_s_setprio(0);
    if (t64 + 2 < 128)
      asm volatile("s_waitcnt vmcnt(6)" ::: "memory");  // drain B(t+1); keep G(t+2)
    else
      asm volatile("s_waitcnt vmcnt(0)" ::: "memory");  // epilogue drain
    __builtin_amdgcn_s_barrier();
  }

  float* ob = out + (size_t)b * 2097152 + (size_t)h * 1024;
#pragma unroll
  for (int mt = 0; mt < 8; ++mt)
#pragma unroll
    for (int nt = 0; nt < 4; ++nt)
#pragma unroll
      for (int r = 0; r < 4; ++r) {
        const int i = wm * 128 + mt * 16 + g * 4 + r;
        const int f = ft * 256 + wn * 64 + nt * 16 + r16;
        ob[(size_t)i * 8192 + f] = acc[mt][nt][r];
      }
}

extern "C" void kernel_launch(void* const* d_in, const int* in_sizes, int n_in,
                              void* d_out, int out_size, void* d_ws, size_t ws_size,
                              hipStream_t stream) {
  const float* img_q = (const float*)d_in[0];
  const float* x = (const float*)d_in[1];
  const float* gamma_q = (const float*)d_in[2];
  const float* gamma_x = (const float*)d_in[3];
  const float* wkv = (const float*)d_in[4];

  float* out_f = (float*)d_out;
  float* attn_f = out_f + OUT_ELEMS;

  // Stashes aliasing not-yet-written d_out regions (all dead before overwrite):
  u16* xn = (u16*)attn_f;        // x_n bf16 [65536][1024], 128MB of attn region
  u16* qsb = (u16*)out_f;        // q bf16 (scaled) [16][256][1024], 8MB
  u16* wtb = qsb + 4194304;      // Wt bf16 [128][1024]
  u16* ksb = wtb + 131072;       // k bf16 [16][4096][128], 16MB
  u16* xnt = (u16*)d_ws;         // x_nT bf16 [16][1024][4096], 128MiB

  if (ws_size < (size_t)134217728) return;  // need x_nT scratch

  ln_rows<<<65536, 256, 0, stream>>>(x, gamma_x, xn, 1.0f);
  ln_rows<<<4096, 256, 0, stream>>>(img_q, gamma_q, qsb, SCALE);
  cvt_w<<<128, 256, 0, stream>>>(wkv, wtb);
  transpose_xn<<<dim3(64, 16, 16), 256, 0, stream>>>(xn, xnt);
  kgemm<<<512, 256, 0, stream>>>(xn, wtb, ksb);
  attn_kernel<<<2048, 1024, 0, stream>>>(qsb, ksb, attn_f);
  ogemm256<<<512, 512, 0, stream>>>(attn_f, xnt, out_f);
}

// Round 7
// 854.981 us; speedup vs baseline: 1.1789x; 1.1789x over previous
//
#include <hip/hip_runtime.h>

typedef unsigned short u16;
typedef unsigned int u32;
typedef __attribute__((ext_vector_type(8))) short short8;
typedef __attribute__((ext_vector_type(4))) float f32x4;
typedef __attribute__((ext_vector_type(4))) unsigned int u32x4;

// Problem constants: B=16, N=256, T=4096, D=1024, H=8, DH=128
#define SCALE 0.08838834764831845f
#define OUT_ELEMS 33554432ull  // 16*256*8*1024

__device__ __forceinline__ u16 f2b(float f) {  // f32 -> bf16 RNE
  u32 u = __float_as_uint(f);
  u32 r = u + 0x7fffu + ((u >> 16) & 1u);
  return (u16)(r >> 16);
}

__device__ __forceinline__ u32 cvtpk(float lo, float hi) {  // 2 f32 -> packed bf16x2 (RNE)
  u32 r;
  asm("v_cvt_pk_bf16_f32 %0, %1, %2" : "=v"(r) : "v"(lo), "v"(hi));
  return r;
}

__device__ __forceinline__ void gload16(const void* g, void* l) {
  // async global->LDS, 16B per lane; LDS dest = wave-uniform base (+ lane*16 by HW)
  __builtin_amdgcn_global_load_lds((const __attribute__((address_space(1))) void*)g,
                                   (__attribute__((address_space(3))) void*)l, 16, 0, 0);
}

__device__ __forceinline__ uint2 shflx2(uint2 v, int m) {
  uint2 r;
  r.x = __shfl_xor(v.x, m, 64);
  r.y = __shfl_xor(v.y, m, 64);
  return r;
}

// ---------------- LayerNorm rows of length 1024 -> bf16 (scale folded) -------
__global__ __launch_bounds__(256) void ln_rows(const float* __restrict__ in,
                                               const float* __restrict__ gamma,
                                               u16* __restrict__ out, float scale) {
  const int row = blockIdx.x;
  const int t = threadIdx.x;
  const float4 v = *(const float4*)(in + (size_t)row * 1024 + t * 4);
  float s = v.x + v.y + v.z + v.w;
  float q = v.x * v.x + v.y * v.y + v.z * v.z + v.w * v.w;
#pragma unroll
  for (int m = 32; m; m >>= 1) {
    s += __shfl_down(s, m);
    q += __shfl_down(q, m);
  }
  __shared__ float red[8];
  const int w = t >> 6;
  if ((t & 63) == 0) { red[w] = s; red[4 + w] = q; }
  __syncthreads();
  s = red[0] + red[1] + red[2] + red[3];
  q = red[4] + red[5] + red[6] + red[7];
  const float mu = s * (1.0f / 1024.0f);
  const float var = q * (1.0f / 1024.0f) - mu * mu;
  const float rs = rsqrtf(var + 1e-5f) * scale;
  const float4 g = *(const float4*)(gamma + t * 4);
  ushort4 o;
  o.x = f2b((v.x - mu) * rs * g.x);
  o.y = f2b((v.y - mu) * rs * g.y);
  o.z = f2b((v.z - mu) * rs * g.z);
  o.w = f2b((v.w - mu) * rs * g.w);
  *(ushort4*)(out + (size_t)row * 1024 + t * 4) = o;
}

// ---------------- W_kv[:, :128] -> Wt bf16 [128][1024] -----------------------
__global__ __launch_bounds__(256) void cvt_w(const float* __restrict__ w, u16* __restrict__ wt) {
  const int n = blockIdx.x;  // 0..127
  const int t = threadIdx.x;
  const int d = t * 4;
  ushort4 o;
  o.x = f2b(w[(size_t)(d + 0) * 256 + n]);
  o.y = f2b(w[(size_t)(d + 1) * 256 + n]);
  o.z = f2b(w[(size_t)(d + 2) * 256 + n]);
  o.w = f2b(w[(size_t)(d + 3) * 256 + n]);
  *(ushort4*)(wt + (size_t)n * 1024 + d) = o;
}

// ---------------- x_n [b][4096][1024] -> x_nT [b][1024][4096] (bf16) ---------
__global__ __launch_bounds__(256) void transpose_xn(const u16* __restrict__ xn,
                                                    u16* __restrict__ xnt) {
  const int jt = blockIdx.x, dt = blockIdx.y, b = blockIdx.z;
  __shared__ u16 tile[64][72];  // pad 8 keeps 16B alignment per row
  const int t = threadIdx.x;
  const size_t src = ((size_t)b * 4096 + jt * 64) * 1024 + dt * 64;
#pragma unroll
  for (int p = 0; p < 2; ++p) {
    const int idx = t + 256 * p;
    const int j = idx >> 3, c = idx & 7;
    *(short8*)(&tile[j][c * 8]) = *(const short8*)(xn + src + (size_t)j * 1024 + c * 8);
  }
  __syncthreads();
  const size_t dst = ((size_t)b * 1024 + dt * 64) * 4096 + jt * 64;
#pragma unroll
  for (int p = 0; p < 2; ++p) {
    const int idx = t + 256 * p;
    const int d = idx >> 3, jj = idx & 7;
    short8 o;
#pragma unroll
    for (int e = 0; e < 8; ++e) o[e] = (short)tile[jj * 8 + e][d];
    *(short8*)(xnt + dst + (size_t)d * 4096 + jj * 8) = o;
  }
}

// ---------------- k = x_n @ W[:, :128]  (M=65536, N=128, K=1024) -------------
__global__ __launch_bounds__(256) void kgemm(const u16* __restrict__ xn,
                                             const u16* __restrict__ wt,
                                             u16* __restrict__ ks) {
  __shared__ u16 As[128 * 32];
  __shared__ u16 Bs[128 * 32];
  const int t = threadIdx.x;
  const int lane = t & 63, w = t >> 6;
  const int wm = w >> 1, wn = w & 1;
  const int j0 = blockIdx.x * 128;
  const int g = lane >> 4, r16 = lane & 15;
  f32x4 acc[4][4] = {};
  for (int k0 = 0; k0 < 1024; k0 += 32) {
    __syncthreads();
#pragma unroll
    for (int i = 0; i < 2; ++i) {
      const int seg = i * 4 + w;
      const int off = seg * 1024 + lane * 16;  // linear LDS byte offset
      const int row = off >> 6;                // 64B per row (32 bf16)
      const int c = (off >> 4) & 3;            // 16B chunk in row
      const int sw = c ^ ((row >> 1) & 3);     // inverse-swizzled global source
      gload16(xn + ((size_t)(j0 + row)) * 1024 + k0 + sw * 8, (char*)As + seg * 1024);
      gload16(wt + ((size_t)row) * 1024 + k0 + sw * 8, (char*)Bs + seg * 1024);
    }
    __syncthreads();
    short8 a[4], bq[4];
#pragma unroll
    for (int mt = 0; mt < 4; ++mt) {
      const int row = wm * 64 + mt * 16 + r16;
      const int sw = g ^ ((row >> 1) & 3);
      a[mt] = *(const short8*)(As + row * 32 + sw * 8);
    }
#pragma unroll
    for (int nt = 0; nt < 4; ++nt) {
      const int row = wn * 64 + nt * 16 + r16;
      const int sw = g ^ ((row >> 1) & 3);
      bq[nt] = *(const short8*)(Bs + row * 32 + sw * 8);
    }
#pragma unroll
    for (int mt = 0; mt < 4; ++mt)
#pragma unroll
      for (int nt = 0; nt < 4; ++nt)
        acc[mt][nt] = __builtin_amdgcn_mfma_f32_16x16x32_bf16(a[mt], bq[nt], acc[mt][nt], 0, 0, 0);
  }
#pragma unroll
  for (int mt = 0; mt < 4; ++mt)
#pragma unroll
    for (int nt = 0; nt < 4; ++nt)
#pragma unroll
      for (int r = 0; r < 4; ++r) {
        const int j = j0 + wm * 64 + mt * 16 + g * 4 + r;
        const int n = wn * 64 + nt * 16 + r16;
        ks[(size_t)j * 128 + n] = f2b(acc[mt][nt][r]);
      }
}

// ---------------- sim + softmax -> attn f32 + attnb bf16 ---------------------
// block = (b, h, 16 q-rows); 16 waves, wave w covers j in [w*256, w*256+256).
// SWAPPED QK^T: lane holds q-row i = r16, j = j0 + nt*16 + g*4 + r.
// bf16 path: 4x4 butterfly transpose across g-lanes -> lane g owns 16
// contiguous j -> full-line dwordx4 stores, no LDS, no lgkm drains.
__global__ __launch_bounds__(1024) void attn_kernel(const u16* __restrict__ qs,
                                                    const u16* __restrict__ ks,
                                                    float* __restrict__ attn,
                                                    u16* __restrict__ attnb) {
  const int blk = blockIdx.x;
  const int it = blk & 15, h = (blk >> 4) & 7, b = blk >> 7;
  const int i0 = it * 16;
  const int t = threadIdx.x;
  const int lane = t & 63, w = t >> 6;
  const int g = lane >> 4, r16 = lane & 15;
  __shared__ u16 Q[16 * 128];
  __shared__ float redm[256];
  __shared__ float reds[256];
  if (t < 256) {
    const int row = t >> 4, c = t & 15;
    const int sw = c ^ (row & 7);
    *(short8*)(Q + row * 128 + sw * 8) =
        *(const short8*)(qs + ((size_t)(b * 256 + i0 + row)) * 1024 + h * 128 + c * 8);
  }
  __syncthreads();
  short8 a[4];
#pragma unroll
  for (int kp = 0; kp < 4; ++kp) {
    const int c = kp * 4 + g;
    const int sw = c ^ (r16 & 7);
    a[kp] = *(const short8*)(Q + r16 * 128 + sw * 8);
  }
  const u16* kb = ks + (size_t)b * 4096 * 128;
  const int j0 = w * 256;
  f32x4 acc[16] = {};
#pragma unroll
  for (int kp = 0; kp < 4; ++kp) {
#pragma unroll
    for (int nt = 0; nt < 16; ++nt) {
      const short8 bv = *(const short8*)(kb + (size_t)(j0 + nt * 16 + r16) * 128 + kp * 32 + g * 8);
      acc[nt] = __builtin_amdgcn_mfma_f32_16x16x32_bf16(bv, a[kp], acc[nt], 0, 0, 0);
    }
  }
  float mx = acc[0][0];
#pragma unroll
  for (int nt = 0; nt < 16; ++nt)
#pragma unroll
    for (int r = 0; r < 4; ++r) mx = fmaxf(mx, acc[nt][r]);
  mx = fmaxf(mx, __shfl_xor(mx, 16));
  mx = fmaxf(mx, __shfl_xor(mx, 32));
  if (lane < 16) redm[w * 16 + lane] = mx;
  __syncthreads();
  float m = redm[r16];
#pragma unroll
  for (int w2 = 1; w2 < 16; ++w2) m = fmaxf(m, redm[w2 * 16 + r16]);
  float sm = 0.f;
#pragma unroll
  for (int nt = 0; nt < 16; ++nt)
#pragma unroll
    for (int r = 0; r < 4; ++r) {
      const float p = __expf(acc[nt][r] - m);
      acc[nt][r] = p;
      sm += p;
    }
  sm += __shfl_xor(sm, 16);
  sm += __shfl_xor(sm, 32);
  if (lane < 16) reds[w * 16 + lane] = sm;
  __syncthreads();
  float s = reds[r16];
#pragma unroll
  for (int w2 = 1; w2 < 16; ++w2) s += reds[w2 * 16 + r16];
  const float inv = 1.0f / s;
#pragma unroll
  for (int nt = 0; nt < 16; ++nt) acc[nt] *= inv;

  // f32 attn: full-line dwordx4 NT stores (streaming, never re-read by us)
  float* arow = attn + ((size_t)((b * 8 + h) * 256 + i0 + r16)) * 4096 + j0;
#pragma unroll
  for (int nt = 0; nt < 16; ++nt)
    __builtin_nontemporal_store(acc[nt], (f32x4*)(arow + nt * 16 + g * 4));

  // bf16 attnb: per 64-j group, 4x4 butterfly transpose across g-lanes.
  // Initial: X[i] = bf16x4 quad (nt'=i, pos=g). Final: X[s] = quad (nt'=g, pos=s)
  // -> lane g holds j = j0 + q4*64 + g*16 + [0,16).
  u16* brow = attnb + ((size_t)((b * 8 + h) * 256 + i0 + r16)) * 4096 + j0;
  const bool gb0 = (g & 1), gb1 = (g & 2);
#pragma unroll
  for (int q4 = 0; q4 < 4; ++q4) {
    uint2 X[4];
#pragma unroll
    for (int i = 0; i < 4; ++i) {
      const f32x4 v = acc[q4 * 4 + i];
      X[i] = make_uint2(cvtpk(v[0], v[1]), cvtpk(v[2], v[3]));
    }
#pragma unroll
    for (int k = 0; k < 2; ++k) {  // stage 1: lane-bit0 <-> index-bit0
      const uint2 aa = X[2 * k], bb = X[2 * k + 1];
      const uint2 sent = gb0 ? aa : bb;
      const uint2 recv = shflx2(sent, 16);
      X[2 * k] = gb0 ? recv : aa;
      X[2 * k + 1] = gb0 ? bb : recv;
    }
#pragma unroll
    for (int k = 0; k < 2; ++k) {  // stage 2: lane-bit1 <-> index-bit1
      const uint2 aa = X[k], bb = X[k + 2];
      const uint2 sent = gb1 ? aa : bb;
      const uint2 recv = shflx2(sent, 32);
      X[k] = gb1 ? recv : aa;
      X[k + 2] = gb1 ? bb : recv;
    }
    u16* bp = brow + q4 * 64 + g * 16;
    u32x4 o0 = {X[0].x, X[0].y, X[1].x, X[1].y};
    u32x4 o1 = {X[2].x, X[2].y, X[3].x, X[3].y};
    __builtin_nontemporal_store(o0, (u32x4*)bp);
    __builtin_nontemporal_store(o1, (u32x4*)(bp + 8));
  }
}

// ---------------- out = attnb @ x_nT  256x256, BK=64, counted-vmcnt ----------
// Per (b,h): C[256 x 1024]. Grid 512 = 16b*8h*4ft. 8 waves (2M x 4N), wave tile
// 128x64, acc[8][4]. 128KB dynamic LDS dbuf; 128B rows, chunk swizzle c^(row&7)
// (R3-proven zero-conflict). Schedule/iter: {reads ks0; lgkm0; 32 MFMA; reads
// ks1; lgkm0; barrier; STAGE(t+2) 8 gloads; 32 MFMA; vmcnt(8); barrier}.
__global__ __launch_bounds__(512, 2) void ogemm256(const u16* __restrict__ attnb,
                                                   const u16* __restrict__ xnt,
                                                   float* __restrict__ out) {
  extern __shared__ u16 S[];  // 128KB: A dbuf bytes [0,64K), B dbuf [64K,128K)
  const int orig = blockIdx.x;
  const int wid = (orig & 7) * 64 + (orig >> 3);  // XCD-chunked, bijective (512%8==0)
  const int b = wid >> 5, ft = (wid >> 3) & 3, h = wid & 7;  // 8 h share B panel
  const int t = threadIdx.x;
  const int lane = t & 63, w = t >> 6;
  const int wm = w >> 2, wn = w & 3;  // 2 x 4 waves
  const int g = lane >> 4, r16 = lane & 15;
  const u16* Ab = attnb + ((size_t)(b * 8 + h) * 256) * 4096;
  const u16* Bb = xnt + ((size_t)b * 1024 + ft * 256) * 4096;

  // Stage coords: granule gi = seg*512+t; row = gi>>3, stored chunk = gi&7,
  // source chunk = (gi&7) ^ (row&7)  (inverse swizzle at the global source).
  int srow[4], scol[4];
#pragma unroll
  for (int seg = 0; seg < 4; ++seg) {
    const int gi = seg * 512 + t;
    srow[seg] = gi >> 3;
    scol[seg] = (((gi & 7) ^ ((gi >> 3) & 7)) * 8);
  }
  const int wuni = w * 1024;  // wave-uniform byte offset within an 8KB seg

#define OSTAGE(buf, k0)                                                         \
  do {                                                                          \
    _Pragma("unroll") for (int seg = 0; seg < 4; ++seg)                         \
        gload16(Ab + (size_t)srow[seg] * 4096 + (k0) + scol[seg],               \
                (char*)S + (buf)*32768 + seg * 8192 + wuni);                    \
    _Pragma("unroll") for (int seg = 0; seg < 4; ++seg)                         \
        gload16(Bb + (size_t)srow[seg] * 4096 + (k0) + scol[seg],               \
                (char*)S + 65536 + (buf)*32768 + seg * 8192 + wuni);            \
  } while (0)

  f32x4 acc[8][4] = {};
  OSTAGE(0, 0);
  OSTAGE(1, 64);
  asm volatile("s_waitcnt vmcnt(8)" ::: "memory");  // tile0 done; tile1 flying
  __builtin_amdgcn_s_barrier();

  for (int t64 = 0; t64 < 64; ++t64) {
    const int buf = t64 & 1;
    const char* A0 = (const char*)S + buf * 32768;
    const char* B0 = (const char*)S + 65536 + buf * 32768;
    short8 af[8], bf[4];
    // ---- ks = 0 frags ----
#pragma unroll
    for (int mt = 0; mt < 8; ++mt) {
      const int row = wm * 128 + mt * 16 + r16;
      af[mt] = *(const short8*)(A0 + row * 128 + ((g ^ (row & 7)) * 16));
    }
#pragma unroll
    for (int nt = 0; nt < 4; ++nt) {
      const int row = wn * 64 + nt * 16 + r16;
      bf[nt] = *(const short8*)(B0 + row * 128 + ((g ^ (row & 7)) * 16));
    }
    asm volatile("s_waitcnt lgkmcnt(0)" ::: "memory");
    __builtin_amdgcn_sched_barrier(0);
    __builtin_amdgcn_s_setprio(1);
#pragma unroll
    for (int mt = 0; mt < 8; ++mt)
#pragma unroll
      for (int nt = 0; nt < 4; ++nt)
        acc[mt][nt] = __builtin_amdgcn_mfma_f32_16x16x32_bf16(af[mt], bf[nt], acc[mt][nt], 0, 0, 0);
    __builtin_amdgcn_s_setprio(0);
    // ---- ks = 1 frags ----
#pragma unroll
    for (int mt = 0; mt < 8; ++mt) {
      const int row = wm * 128 + mt * 16 + r16;
      af[mt] = *(const short8*)(A0 + row * 128 + (((4 + g) ^ (row & 7)) * 16));
    }
#pragma unroll
    for (int nt = 0; nt < 4; ++nt) {
      const int row = wn * 64 + nt * 16 + r16;
      bf[nt] = *(const short8*)(B0 + row * 128 + (((4 + g) ^ (row & 7)) * 16));
    }
    asm volatile("s_waitcnt lgkmcnt(0)" ::: "memory");
    __builtin_amdgcn_sched_barrier(0);
    __builtin_amdgcn_s_barrier();  // all waves done reading buf -> restage ok
    if (t64 + 2 < 64) OSTAGE(buf, (t64 + 2) * 64);
    __builtin_amdgcn_s_setprio(1);
#pragma unroll
    for (int mt = 0; mt < 8; ++mt)
#pragma unroll
      for (int nt = 0; nt < 4; ++nt)
        acc[mt][nt] = __builtin_amdgcn_mfma_f32_16x16x32_bf16(af[mt], bf[nt], acc[mt][nt], 0, 0, 0);
    __builtin_amdgcn_s_setprio(0);
    if (t64 + 2 < 64)
      asm volatile("s_waitcnt vmcnt(8)" ::: "memory");  // t+1 landed; t+2 flying
    else if (t64 == 62)
      asm volatile("s_waitcnt vmcnt(0)" ::: "memory");  // drain last tile
    __builtin_amdgcn_s_barrier();
  }
#undef OSTAGE

  float* ob = out + (size_t)b * 2097152 + (size_t)h * 1024;
#pragma unroll
  for (int mt = 0; mt < 8; ++mt)
#pragma unroll
    for (int nt = 0; nt < 4; ++nt)
#pragma unroll
      for (int r = 0; r < 4; ++r) {
        const int i = wm * 128 + mt * 16 + g * 4 + r;
        const int f = ft * 256 + wn * 64 + nt * 16 + r16;
        ob[(size_t)i * 8192 + f] = acc[mt][nt][r];
      }
}

extern "C" void kernel_launch(void* const* d_in, const int* in_sizes, int n_in,
                              void* d_out, int out_size, void* d_ws, size_t ws_size,
                              hipStream_t stream) {
  const float* img_q = (const float*)d_in[0];
  const float* x = (const float*)d_in[1];
  const float* gamma_q = (const float*)d_in[2];
  const float* gamma_x = (const float*)d_in[3];
  const float* wkv = (const float*)d_in[4];

  float* out_f = (float*)d_out;
  float* attn_f = out_f + OUT_ELEMS;

  // Stashes aliasing not-yet-written d_out regions (all dead before overwrite):
  u16* xn = (u16*)attn_f;        // x_n bf16 [65536][1024], 128MB of attn region
  u16* qsb = (u16*)out_f;        // q bf16 (scaled) [16][256][1024], 8MB
  u16* wtb = qsb + 4194304;      // Wt bf16 [128][1024]
  u16* ksb = wtb + 131072;       // k bf16 [16][4096][128], 16MB
  u16* xnt = (u16*)d_ws;         // x_nT bf16 [16][1024][4096], 128MiB
  u16* attnb = xnt + 67108864;   // attn bf16 [16][8][256][4096], 256MiB

  if (ws_size < (size_t)402653184) return;  // need 384MiB (confirmed R2-R4)

  (void)hipFuncSetAttribute((const void*)ogemm256,
                            hipFuncAttributeMaxDynamicSharedMemorySize, 131072);

  ln_rows<<<65536, 256, 0, stream>>>(x, gamma_x, xn, 1.0f);
  ln_rows<<<4096, 256, 0, stream>>>(img_q, gamma_q, qsb, SCALE);
  cvt_w<<<128, 256, 0, stream>>>(wkv, wtb);
  transpose_xn<<<dim3(64, 16, 16), 256, 0, stream>>>(xn, xnt);
  kgemm<<<512, 256, 0, stream>>>(xn, wtb, ksb);
  attn_kernel<<<2048, 1024, 0, stream>>>(qsb, ksb, attn_f, attnb);
  ogemm256<<<512, 512, 131072, stream>>>(attnb, xnt, out_f);
}